// Round 1
// baseline (2646.321 us; speedup 1.0000x reference)
//
#include <hip/hip_runtime.h>
#include <hip/hip_bf16.h>

typedef unsigned short u16;
typedef unsigned int u32;

#define EPSV 1e-5f
// ws layout (bytes)
#define WS_A3    0        // 128*8 f32 folded A3 = diag(s3)*wA*diag(s2*s1)
#define WS_C3    4096     // 128 f32  c3 = s3*(wA@beta2)+beta3
#define WS_A1    4608     // 128*8 f32 folded direct path
#define WS_BIAS  8704     // 128 f32  total bias
#define WS_WB    9216     // 128*128 bf16 wB
#define WS_WF2   41984    // 128*128 bf16 wf[:,128:]
#define WS_Q     74752    // 2*65536*128 bf16 q = A3 @ x  (33.55 MB)

__device__ __forceinline__ float bf2f(u16 u) { return __uint_as_float(((u32)u) << 16); }
__device__ __forceinline__ u16 f2bf(float f) {
    union { __hip_bfloat16 h; u16 u; } cv;
    cv.h = __float2bfloat16(f);
    return cv.u;
}

// ---------------- prep: fold all BN/affine constants, cast weights to bf16 ----------
__global__ __launch_bounds__(128) void prep_kernel(
    const float* g1, const float* b1, const float* m1, const float* v1,
    const float* w1, const float* c1b,
    const float* g2, const float* b2, const float* m2, const float* v2,
    const float* wA,
    const float* g3, const float* b3, const float* m3, const float* v3,
    const float* wB, const float* wf, const float* bfv,
    float* ws, u16* wBh, u16* wfh)
{
    __shared__ float s1[8], be1[8], s2[8], be2[8];
    int o = threadIdx.x;  // 0..127
    if (o < 8) {
        float s = g1[o] * rsqrtf(v1[o] + EPSV); s1[o] = s; be1[o] = b1[o] - m1[o] * s;
        float t = g2[o] * rsqrtf(v2[o] + EPSV); s2[o] = t; be2[o] = b2[o] - m2[o] * t;
    }
    __syncthreads();
    float s3 = g3[o] * rsqrtf(v3[o] + EPSV);
    float be3 = b3[o] - m3[o] * s3;
    float* A3 = ws;             // float idx 0
    float* c3 = ws + 1024;
    float* A1 = ws + 1152;
    float* bias = ws + 2176;

    float csum = 0.f;
    #pragma unroll
    for (int i = 0; i < 8; i++) {
        float w = wA[o * 8 + i];
        A3[o * 8 + i] = s3 * w * s2[i] * s1[i];
        csum += w * be2[i];
    }
    c3[o] = s3 * csum + be3;

    float w1f[8];
    #pragma unroll
    for (int i = 0; i < 8; i++) w1f[i] = 0.f;
    float cb = 0.f;
    for (int c = 0; c < 128; c++) {
        float f = wf[o * 256 + c];
        #pragma unroll
        for (int i = 0; i < 8; i++) w1f[i] += f * w1[c * 8 + i];
        cb += f * c1b[c];
    }
    float bs = bfv[o] + cb;
    #pragma unroll
    for (int i = 0; i < 8; i++) {
        bs += w1f[i] * be1[i];
        A1[o * 8 + i] = w1f[i] * s1[i];
    }
    bias[o] = bs;

    for (int c = 0; c < 128; c++) {
        wBh[o * 128 + c] = f2bf(wB[o * 128 + c]);
        wfh[o * 128 + c] = f2bf(wf[o * 256 + 128 + c]);
    }
}

// ---------------- q = A3 @ x : per point a 128-vector, stored bf16 --------------------
__global__ __launch_bounds__(256) void q_kernel(const float* __restrict__ x,
                                                const float* __restrict__ ws,
                                                u16* __restrict__ q)
{
    int t = blockIdx.x * 256 + threadIdx.x;   // 131072*64 threads
    int pt = t >> 6;                           // point (b*65536+n), wave-uniform
    int o = (t & 63) * 2;
    int b = pt >> 16, n = pt & 65535;
    const float* A3 = ws;
    float xv[8];
    #pragma unroll
    for (int i = 0; i < 8; i++) xv[i] = x[(((b << 3) + i) << 16) | n];
    float q0 = 0.f, q1 = 0.f;
    #pragma unroll
    for (int i = 0; i < 8; i++) {
        q0 += A3[o * 8 + i] * xv[i];
        q1 += A3[(o + 1) * 8 + i] * xv[i];
    }
    u32 pk = ((u32)f2bf(q0)) | (((u32)f2bf(q1)) << 16);
    ((u32*)q)[t] = pk;   // == element pt*64 + lane
}

// ---------------- heavy: per point z-panel -> wB dots -> max_k -> WF2 + direct -------
__global__ __launch_bounds__(128) void heavy_kernel(
    const u16* __restrict__ q, const int* __restrict__ nbr,
    const u16* __restrict__ wBh, const u16* __restrict__ wfh,
    const float* __restrict__ ws, const float* __restrict__ x,
    float* __restrict__ out)
{
    __shared__ float zbuf[15][128];
    __shared__ float qcn[128];
    __shared__ float NEs[128];
    __shared__ float outb[128][17];   // +1 pad: conflict-free transpose staging
    __shared__ int idxs[15];
    __shared__ float x8v[8];

    const float* c3 = ws + 1024;
    const float* A1 = ws + 1152;
    const float* bias = ws + 2176;
    int tid = threadIdx.x;              // = output channel o
    int ptBase = blockIdx.x * 16;       // 16 points per block (never straddles b)
    int b0 = ptBase >> 16, n0 = ptBase & 65535;

    float a1r[8];
    #pragma unroll
    for (int i = 0; i < 8; i++) a1r[i] = A1[tid * 8 + i];
    float biasv = bias[tid];
    float c3v = c3[tid];
    const uint4* wbrow = (const uint4*)(wBh + tid * 128);  // this thread's wB row, bf16
    const uint4* wfrow = (const uint4*)(wfh + tid * 128);

    for (int pp = 0; pp < 16; pp++) {
        int pt = ptBase + pp;
        int n = n0 + pp;
        __syncthreads();  // protect smem rewrite vs prior iteration readers
        if (tid < 15) idxs[tid] = nbr[(((b0 << 4) + tid + 1) << 16) | n];
        if (tid >= 16 && tid < 24) x8v[tid - 16] = x[(((b0 << 3) + (tid - 16)) << 16) | n];
        qcn[tid] = c3v - bf2f(q[pt * 128 + tid]);   // c3 - q_center
        __syncthreads();
        // phase 1: z_k = relu(q[idx_k] - q_c + c3)
        int rb = b0 << 16;
        #pragma unroll
        for (int k = 0; k < 15; k++) {
            int row = rb | idxs[k];
            zbuf[k][tid] = fmaxf(bf2f(q[row * 128 + tid]) + qcn[tid], 0.f);
        }
        __syncthreads();
        // phase 2: H[o][k] = wB[o,:] . z[k,:]  (z reads are wave-broadcast, free)
        float acc[15];
        #pragma unroll
        for (int k = 0; k < 15; k++) acc[k] = 0.f;
        for (int c8 = 0; c8 < 16; c8++) {
            uint4 W = wbrow[c8];
            float w0 = __uint_as_float(W.x << 16), w1 = __uint_as_float(W.x & 0xffff0000u);
            float w2 = __uint_as_float(W.y << 16), w3 = __uint_as_float(W.y & 0xffff0000u);
            float w4 = __uint_as_float(W.z << 16), w5 = __uint_as_float(W.z & 0xffff0000u);
            float w6 = __uint_as_float(W.w << 16), w7 = __uint_as_float(W.w & 0xffff0000u);
            #pragma unroll
            for (int k = 0; k < 15; k++) {
                const float4* z4 = (const float4*)&zbuf[k][c8 * 8];
                float4 za = z4[0], zb = z4[1];
                acc[k] += w0 * za.x + w1 * za.y + w2 * za.z + w3 * za.w
                        + w4 * zb.x + w5 * zb.y + w6 * zb.z + w7 * zb.w;
            }
        }
        float ne = acc[0];
        #pragma unroll
        for (int k = 1; k < 15; k++) ne = fmaxf(ne, acc[k]);
        NEs[tid] = ne;
        __syncthreads();
        // phase 3: out = bias + A1.x + WF2 . NE
        float ov = biasv;
        #pragma unroll
        for (int i = 0; i < 8; i++) ov += a1r[i] * x8v[i];
        for (int c8 = 0; c8 < 16; c8++) {
            uint4 W = wfrow[c8];
            float w0 = __uint_as_float(W.x << 16), w1 = __uint_as_float(W.x & 0xffff0000u);
            float w2 = __uint_as_float(W.y << 16), w3 = __uint_as_float(W.y & 0xffff0000u);
            float w4 = __uint_as_float(W.z << 16), w5 = __uint_as_float(W.z & 0xffff0000u);
            float w6 = __uint_as_float(W.w << 16), w7 = __uint_as_float(W.w & 0xffff0000u);
            const float4* n4 = (const float4*)&NEs[c8 * 8];
            float4 na = n4[0], nb = n4[1];
            ov += w0 * na.x + w1 * na.y + w2 * na.z + w3 * na.w
                + w4 * nb.x + w5 * nb.y + w6 * nb.z + w7 * nb.w;
        }
        outb[tid][pp] = ov;
    }
    __syncthreads();
    // transposed store: 16 consecutive n per row -> 64B transactions
    #pragma unroll
    for (int r = 0; r < 16; r++) {
        int o = (r << 3) + (tid >> 4);
        int j = tid & 15;
        out[(((b0 << 7) | o) << 16) | (n0 + j)] = outb[o][j];
    }
}

extern "C" void kernel_launch(void* const* d_in, const int* in_sizes, int n_in,
                              void* d_out, int out_size, void* d_ws, size_t ws_size,
                              hipStream_t stream) {
    const float* x   = (const float*)d_in[0];
    const int*   nbr = (const int*)d_in[1];
    const float* g1  = (const float*)d_in[2];
    const float* b1  = (const float*)d_in[3];
    const float* m1  = (const float*)d_in[4];
    const float* v1  = (const float*)d_in[5];
    const float* w1  = (const float*)d_in[6];
    const float* c1b = (const float*)d_in[7];
    const float* g2  = (const float*)d_in[8];
    const float* b2  = (const float*)d_in[9];
    const float* m2  = (const float*)d_in[10];
    const float* v2  = (const float*)d_in[11];
    const float* wA  = (const float*)d_in[12];
    const float* g3  = (const float*)d_in[13];
    const float* b3  = (const float*)d_in[14];
    const float* m3  = (const float*)d_in[15];
    const float* v3  = (const float*)d_in[16];
    const float* wB  = (const float*)d_in[17];
    const float* wf  = (const float*)d_in[18];
    const float* bfv = (const float*)d_in[19];

    float* ws  = (float*)d_ws;
    u16*   wBh = (u16*)((char*)d_ws + WS_WB);
    u16*   wfh = (u16*)((char*)d_ws + WS_WF2);
    u16*   q   = (u16*)((char*)d_ws + WS_Q);
    float* out = (float*)d_out;

    prep_kernel<<<1, 128, 0, stream>>>(g1, b1, m1, v1, w1, c1b, g2, b2, m2, v2,
                                       wA, g3, b3, m3, v3, wB, wf, bfv, ws, wBh, wfh);
    q_kernel<<<32768, 256, 0, stream>>>(x, ws, q);
    heavy_kernel<<<8192, 128, 0, stream>>>(q, nbr, wBh, wfh, ws, x, out);
}

// Round 2
// 361.298 us; speedup vs baseline: 7.3245x; 7.3245x over previous
//
#include <hip/hip_runtime.h>
#include <hip/hip_bf16.h>

typedef unsigned short u16;
typedef unsigned int u32;
typedef short bf16x8 __attribute__((ext_vector_type(8)));
typedef float f32x4 __attribute__((ext_vector_type(4)));

#define EPSV 1e-5f
// ws byte layout
#define WS_A3    0          // 128*8 f32  A3 = diag(s3)*wA*diag(s2*s1)
#define WS_C3    4096       // 128 f32    c3
#define WS_WB    4608       // 128*128 bf16 wB
#define WS_WCAT  37376      // 128*160 bf16 [wf2 | A1 | bias | 0]
#define WS_Q     78336      // 2*65536*128 bf16 q = A3 @ x

union U4 { uint4 q; bf16x8 v; };

__device__ __forceinline__ u16 f2bf(float f) {
    union { __hip_bfloat16 h; u16 u; } cv;
    cv.h = __float2bfloat16(f);
    return cv.u;
}
__device__ __forceinline__ u32 pack_rne(float a, float b) {
    u32 ua = __float_as_uint(a), ub = __float_as_uint(b);
    ua = ua + 0x7FFFu + ((ua >> 16) & 1u);
    ub = ub + 0x7FFFu + ((ub >> 16) & 1u);
    return (ua >> 16) | (ub & 0xFFFF0000u);
}

// ---------------- prep: fold constants, build Wcat = [wf2 | A1 | bias | 0] ----------
__global__ __launch_bounds__(128) void prep_kernel(
    const float* g1, const float* b1, const float* m1, const float* v1,
    const float* w1, const float* c1b,
    const float* g2, const float* b2, const float* m2, const float* v2,
    const float* wA,
    const float* g3, const float* b3, const float* m3, const float* v3,
    const float* wB, const float* wf, const float* bfv,
    float* ws, u16* wBh, u16* Wc)
{
    __shared__ float s1[8], be1[8], s2[8], be2[8];
    int o = threadIdx.x;  // 0..127
    if (o < 8) {
        float s = g1[o] * rsqrtf(v1[o] + EPSV); s1[o] = s; be1[o] = b1[o] - m1[o] * s;
        float t = g2[o] * rsqrtf(v2[o] + EPSV); s2[o] = t; be2[o] = b2[o] - m2[o] * t;
    }
    __syncthreads();
    float s3 = g3[o] * rsqrtf(v3[o] + EPSV);
    float be3 = b3[o] - m3[o] * s3;
    float* A3 = ws;            // float idx 0
    float* c3 = ws + 1024;     // float idx 1024

    float csum = 0.f;
    #pragma unroll
    for (int i = 0; i < 8; i++) {
        float w = wA[o * 8 + i];
        A3[o * 8 + i] = s3 * w * s2[i] * s1[i];
        csum += w * be2[i];
    }
    c3[o] = s3 * csum + be3;

    // direct path fold: A1 = (wf_left @ w1) * s1,  bias = bf + wf_left@c1b + A1@(be1/s1...)
    float w1f[8];
    #pragma unroll
    for (int i = 0; i < 8; i++) w1f[i] = 0.f;
    float cb = 0.f;
    for (int c = 0; c < 128; c++) {
        float f = wf[o * 256 + c];
        #pragma unroll
        for (int i = 0; i < 8; i++) w1f[i] += f * w1[c * 8 + i];
        cb += f * c1b[c];
    }
    float bs = bfv[o] + cb;
    #pragma unroll
    for (int i = 0; i < 8; i++) bs += w1f[i] * be1[i];

    for (int c = 0; c < 128; c++) {
        wBh[o * 128 + c] = f2bf(wB[o * 128 + c]);
        Wc[o * 160 + c]  = f2bf(wf[o * 256 + 128 + c]);
    }
    #pragma unroll
    for (int i = 0; i < 8; i++) Wc[o * 160 + 128 + i] = f2bf(w1f[i] * s1[i]);
    Wc[o * 160 + 136] = f2bf(bs);
    for (int k = 137; k < 160; k++) Wc[o * 160 + k] = 0;
}

// ---------------- q = A3 @ x : per point 128 bf16 --------------------
__global__ __launch_bounds__(256) void q_kernel(const float* __restrict__ x,
                                                const float* __restrict__ ws,
                                                u16* __restrict__ q)
{
    int t = blockIdx.x * 256 + threadIdx.x;
    int pt = t >> 6;
    int o = (t & 63) * 2;
    int b = pt >> 16, n = pt & 65535;
    const float* A3 = ws;
    float xv[8];
    #pragma unroll
    for (int i = 0; i < 8; i++) xv[i] = x[(((b << 3) + i) << 16) | n];
    float q0 = 0.f, q1 = 0.f;
    #pragma unroll
    for (int i = 0; i < 8; i++) {
        q0 += A3[o * 8 + i] * xv[i];
        q1 += A3[(o + 1) * 8 + i] * xv[i];
    }
    ((u32*)q)[t] = pack_rne(q0, q1);
}

// ---------------- heavy: MFMA edge-conv ----------------
// block 256 = 4 waves; per group of 16 points:
//   2 sub-iters of 8 points: Z^T panel (128 cols x 128 c bf16) in LDS,
//   H^T = Z^T * wB^T via mfma (slots on rows -> cheap k-max), NE -> LDS bf16,
//   then phase3: out = Wcat * [NE; x; 1]  (M=o' split across waves).
__global__ __launch_bounds__(256, 2) void heavy_kernel(
    const u16* __restrict__ q, const int* __restrict__ nbr,
    const u16* __restrict__ wBh, const u16* __restrict__ Wcat,
    const float* __restrict__ ws, const float* __restrict__ x,
    float* __restrict__ out)
{
    __shared__ uint4 Zb[128 * 17];     // col-stride 17 granules (16B) -> conflict-free
    __shared__ uint4 NExq[16 * 21];    // per point: 160 bf16 (NE|x|1|0), stride 21 granules
    __shared__ int idxb[256];          // [pt16][slot]

    u16* NEp = (u16*)NExq;
    const uint4* qv = (const uint4*)q;

    int tid = threadIdx.x;
    int w = tid >> 6, l = tid & 63;
    int quad = l >> 4, l15 = l & 15;
    int wm = w >> 1, wn = w & 1;       // phase-2 wave grid: points x o-half

    // persistent wB^T fragments: B[k=c][n=o], lane: wB[o=wn*64+nt*16+l15][c=kt*32+quad*8+j]
    bf16x8 wBf[4][4];
    #pragma unroll
    for (int nt = 0; nt < 4; nt++)
        #pragma unroll
        for (int kt = 0; kt < 4; kt++) {
            U4 u; u.q = *(const uint4*)(wBh + (wn * 64 + nt * 16 + l15) * 128 + kt * 32 + quad * 8);
            wBf[nt][kt] = u.v;
        }
    // persistent Wcat A-fragments: A[m=o'][k], lane: Wcat[wv*32+mt*16+l15][kt*32+quad*8+j]
    bf16x8 Wcf[2][5];
    #pragma unroll
    for (int mt = 0; mt < 2; mt++)
        #pragma unroll
        for (int kt = 0; kt < 5; kt++) {
            U4 u; u.q = *(const uint4*)(Wcat + (w * 32 + mt * 16 + l15) * 160 + kt * 32 + quad * 8);
            Wcf[mt][kt] = u.v;
        }

    // z-build persona
    int pt_l = tid >> 5;               // 0..7
    int sub = tid & 31;
    int g = sub & 15;                  // granule = c/8
    int shalf = sub >> 4;              // slots shalf*8 .. +7
    float c3r[8];
    {
        float4 ca = *(const float4*)(ws + 1024 + g * 8);
        float4 cb = *(const float4*)(ws + 1024 + g * 8 + 4);
        c3r[0] = ca.x; c3r[1] = ca.y; c3r[2] = ca.z; c3r[3] = ca.w;
        c3r[4] = cb.x; c3r[5] = cb.y; c3r[6] = cb.z; c3r[7] = cb.w;
    }

    for (int it = 0; it < 4; ++it) {
        int group = blockIdx.x * 4 + it;         // 8192 groups total
        int b = group >> 12;                     // 4096 groups per batch
        int n0 = (group & 4095) << 4;

        __syncthreads();   // protect idxb/NExq rewrite vs previous phase-3 readers
        // stage neighbor indices: [pt16][slot], slot 15 duplicates slot 0
        {
            int slot = tid >> 4, pt = tid & 15;
            int srow = (slot < 15) ? slot + 1 : 1;
            idxb[pt * 16 + slot] = nbr[((b * 16 + srow) << 16) + n0 + pt];
        }
        // stage NEx static tail: x (bf16) at k=128..135, 1.0 at k=136, zeros after
        if (tid < 16) {
            int pt = tid;
            float xv[8];
            #pragma unroll
            for (int i = 0; i < 8; i++) xv[i] = x[((b * 8 + i) << 16) + n0 + pt];
            uint4 wx;
            wx.x = pack_rne(xv[0], xv[1]); wx.y = pack_rne(xv[2], xv[3]);
            wx.z = pack_rne(xv[4], xv[5]); wx.w = pack_rne(xv[6], xv[7]);
            NExq[pt * 21 + 16] = wx;
            NExq[pt * 21 + 17] = make_uint4(0x3F80u, 0u, 0u, 0u);
            NExq[pt * 21 + 18] = make_uint4(0u, 0u, 0u, 0u);
            NExq[pt * 21 + 19] = make_uint4(0u, 0u, 0u, 0u);
        }

        for (int s = 0; s < 2; ++s) {
            __syncthreads();   // staging done / previous GEMM reads of Zb done
            // ---- z-build: Z[col=pt_l*16+slot][c] = relu(q_nbr - q_ctr + c3), bf16
            int cpt = s * 8 + pt_l;
            uint4 qc = qv[(size_t)((b << 16) + n0 + cpt) * 16 + g];
            float D[8];
            D[0] = c3r[0] - __uint_as_float(qc.x << 16);
            D[1] = c3r[1] - __uint_as_float(qc.x & 0xFFFF0000u);
            D[2] = c3r[2] - __uint_as_float(qc.y << 16);
            D[3] = c3r[3] - __uint_as_float(qc.y & 0xFFFF0000u);
            D[4] = c3r[4] - __uint_as_float(qc.z << 16);
            D[5] = c3r[5] - __uint_as_float(qc.z & 0xFFFF0000u);
            D[6] = c3r[6] - __uint_as_float(qc.w << 16);
            D[7] = c3r[7] - __uint_as_float(qc.w & 0xFFFF0000u);
            #pragma unroll
            for (int i = 0; i < 8; i++) {
                int slot = shalf * 8 + i;
                int idx = idxb[cpt * 16 + slot];
                uint4 qn = qv[(size_t)((b << 16) + idx) * 16 + g];
                float z0 = fmaxf(__uint_as_float(qn.x << 16)          + D[0], 0.f);
                float z1 = fmaxf(__uint_as_float(qn.x & 0xFFFF0000u)  + D[1], 0.f);
                float z2 = fmaxf(__uint_as_float(qn.y << 16)          + D[2], 0.f);
                float z3 = fmaxf(__uint_as_float(qn.y & 0xFFFF0000u)  + D[3], 0.f);
                float z4 = fmaxf(__uint_as_float(qn.z << 16)          + D[4], 0.f);
                float z5 = fmaxf(__uint_as_float(qn.z & 0xFFFF0000u)  + D[5], 0.f);
                float z6 = fmaxf(__uint_as_float(qn.w << 16)          + D[6], 0.f);
                float z7 = fmaxf(__uint_as_float(qn.w & 0xFFFF0000u)  + D[7], 0.f);
                uint4 wz;
                wz.x = pack_rne(z0, z1); wz.y = pack_rne(z2, z3);
                wz.z = pack_rne(z4, z5); wz.w = pack_rne(z6, z7);
                Zb[(pt_l * 16 + slot) * 17 + g] = wz;
            }
            __syncthreads();
            // ---- GEMM: H^T[slot][o] per point; rows=slots -> cheap max
            #pragma unroll
            for (int p = 0; p < 4; ++p) {
                int colb = (wm * 4 + p) * 16;
                f32x4 acc[4];
                #pragma unroll
                for (int nt = 0; nt < 4; nt++) acc[nt] = (f32x4){0.f, 0.f, 0.f, 0.f};
                #pragma unroll
                for (int kt = 0; kt < 4; ++kt) {
                    U4 u; u.q = Zb[(colb + l15) * 17 + kt * 4 + quad];
                    #pragma unroll
                    for (int nt = 0; nt < 4; nt++)
                        acc[nt] = __builtin_amdgcn_mfma_f32_16x16x32_bf16(u.v, wBf[nt][kt], acc[nt], 0, 0, 0);
                }
                int pt16 = s * 8 + wm * 4 + p;
                #pragma unroll
                for (int nt = 0; nt < 4; nt++) {
                    float m = fmaxf(fmaxf(acc[nt][0], acc[nt][1]), fmaxf(acc[nt][2], acc[nt][3]));
                    m = fmaxf(m, __shfl_xor(m, 16, 64));
                    m = fmaxf(m, __shfl_xor(m, 32, 64));
                    if (l < 16) {
                        u32 um = __float_as_uint(m);
                        um = um + 0x7FFFu + ((um >> 16) & 1u);
                        NEp[pt16 * 168 + wn * 64 + nt * 16 + l] = (u16)(um >> 16);
                    }
                }
            }
        }
        __syncthreads();   // NE complete
        // ---- phase 3: out[o'][pt] = Wcat . [NE; x; 1; 0]
        f32x4 oa[2];
        oa[0] = (f32x4){0.f, 0.f, 0.f, 0.f};
        oa[1] = (f32x4){0.f, 0.f, 0.f, 0.f};
        #pragma unroll
        for (int kt = 0; kt < 5; ++kt) {
            U4 u; u.q = NExq[l15 * 21 + kt * 4 + quad];
            oa[0] = __builtin_amdgcn_mfma_f32_16x16x32_bf16(Wcf[0][kt], u.v, oa[0], 0, 0, 0);
            oa[1] = __builtin_amdgcn_mfma_f32_16x16x32_bf16(Wcf[1][kt], u.v, oa[1], 0, 0, 0);
        }
        #pragma unroll
        for (int mt = 0; mt < 2; ++mt) {
            int ob = w * 32 + mt * 16 + quad * 4;
            #pragma unroll
            for (int r = 0; r < 4; ++r)
                out[(((b << 7) + ob + r) << 16) + n0 + l15] = oa[mt][r];
        }
    }
}

extern "C" void kernel_launch(void* const* d_in, const int* in_sizes, int n_in,
                              void* d_out, int out_size, void* d_ws, size_t ws_size,
                              hipStream_t stream) {
    const float* x   = (const float*)d_in[0];
    const int*   nbr = (const int*)d_in[1];
    const float* g1  = (const float*)d_in[2];
    const float* b1  = (const float*)d_in[3];
    const float* m1  = (const float*)d_in[4];
    const float* v1  = (const float*)d_in[5];
    const float* w1  = (const float*)d_in[6];
    const float* c1b = (const float*)d_in[7];
    const float* g2  = (const float*)d_in[8];
    const float* b2  = (const float*)d_in[9];
    const float* m2  = (const float*)d_in[10];
    const float* v2  = (const float*)d_in[11];
    const float* wA  = (const float*)d_in[12];
    const float* g3  = (const float*)d_in[13];
    const float* b3  = (const float*)d_in[14];
    const float* m3  = (const float*)d_in[15];
    const float* v3  = (const float*)d_in[16];
    const float* wB  = (const float*)d_in[17];
    const float* wf  = (const float*)d_in[18];
    const float* bfv = (const float*)d_in[19];

    float* wsF  = (float*)d_ws;
    u16*   wBh  = (u16*)((char*)d_ws + WS_WB);
    u16*   Wcat = (u16*)((char*)d_ws + WS_WCAT);
    u16*   q    = (u16*)((char*)d_ws + WS_Q);
    float* out  = (float*)d_out;

    prep_kernel<<<1, 128, 0, stream>>>(g1, b1, m1, v1, w1, c1b, g2, b2, m2, v2,
                                       wA, g3, b3, m3, v3, wB, wf, bfv, wsF, wBh, Wcat);
    q_kernel<<<32768, 256, 0, stream>>>(x, wsF, q);
    heavy_kernel<<<2048, 256, 0, stream>>>(q, nbr, wBh, Wcat, wsF, x, out);
}

// Round 4
// 361.251 us; speedup vs baseline: 7.3254x; 1.0001x over previous
//
#include <hip/hip_runtime.h>
#include <hip/hip_bf16.h>

typedef unsigned short u16;
typedef unsigned int u32;
typedef short bf16x8 __attribute__((ext_vector_type(8)));
typedef float f32x4 __attribute__((ext_vector_type(4)));

#define EPSV 1e-5f
// ws byte layout
#define WS_A3    0                       // 128*8 f32
#define WS_C3    4096                    // 128 f32
#define WS_C3BF  4608                    // 128 bf16
#define WS_WB    4864                    // 128*128 bf16
#define WS_WCAT  37632                   // 128*160 bf16 [wf2 | A1 | bias | 0]
#define WS_Q     78592                   // 33.55 MB bf16 q = A3@x
#define WS_NE    (78592 + 33554432)      // 33.55 MB bf16 NE

union U4 { uint4 q; bf16x8 v; };

__device__ __forceinline__ u16 f2bf(float f) {
    union { __hip_bfloat16 h; u16 u; } cv;
    cv.h = __float2bfloat16(f);
    return cv.u;
}
__device__ __forceinline__ u32 pack_rne(float a, float b) {
    u32 ua = __float_as_uint(a), ub = __float_as_uint(b);
    ua = ua + 0x7FFFu + ((ua >> 16) & 1u);
    ub = ub + 0x7FFFu + ((ub >> 16) & 1u);
    return (ua >> 16) | (ub & 0xFFFF0000u);
}
// z = relu(bf(a_half) + bf(d_half)), packed bf16 (round-half-up + v_perm)
__device__ __forceinline__ u32 zpair(u32 a, u32 d) {
    float lo = __uint_as_float(a << 16) + __uint_as_float(d << 16);
    float hi = __uint_as_float(a & 0xFFFF0000u) + __uint_as_float(d & 0xFFFF0000u);
    lo = fmaxf(lo, 0.f);
    hi = fmaxf(hi, 0.f);
    return __builtin_amdgcn_perm(__float_as_uint(hi) + 0x8000u,
                                 __float_as_uint(lo) + 0x8000u, 0x07060302u);
}
// d = bf(c_half) - bf(q_half), packed bf16
__device__ __forceinline__ u32 dpair(u32 c, u32 qc) {
    float lo = __uint_as_float(c << 16) - __uint_as_float(qc << 16);
    float hi = __uint_as_float(c & 0xFFFF0000u) - __uint_as_float(qc & 0xFFFF0000u);
    return pack_rne(lo, hi);
}

// ---------------- prep: fold constants ----------------
__global__ __launch_bounds__(256) void prep_kernel(
    const float* g1, const float* b1, const float* m1, const float* v1,
    const float* w1, const float* c1b,
    const float* g2, const float* b2, const float* m2, const float* v2,
    const float* wA,
    const float* g3, const float* b3, const float* m3, const float* v3,
    const float* wB, const float* wf, const float* bfv,
    float* ws, u16* c3bf, u16* wBh, u16* Wc)
{
    __shared__ float w1s[1024];
    __shared__ float s1[8], be1[8], s2[8], be2[8];
    int t = threadIdx.x;
    for (int i = t; i < 1024; i += 256) w1s[i] = w1[i];
    if (t < 8) {
        float s = g1[t] * rsqrtf(v1[t] + EPSV); s1[t] = s; be1[t] = b1[t] - m1[t] * s;
        float u = g2[t] * rsqrtf(v2[t] + EPSV); s2[t] = u; be2[t] = b2[t] - m2[t] * u;
    }
    __syncthreads();
    if (t < 128) {
        int o = t;
        float s3 = g3[o] * rsqrtf(v3[o] + EPSV);
        float be3 = b3[o] - m3[o] * s3;
        float* A3 = ws;
        float* c3 = ws + 1024;
        float csum = 0.f;
        #pragma unroll
        for (int i = 0; i < 8; i++) {
            float w = wA[o * 8 + i];
            A3[o * 8 + i] = s3 * w * s2[i] * s1[i];
            csum += w * be2[i];
        }
        float c3v = s3 * csum + be3;
        c3[o] = c3v;
        c3bf[o] = f2bf(c3v);

        float w1f[8];
        #pragma unroll
        for (int i = 0; i < 8; i++) w1f[i] = 0.f;
        float cb = 0.f;
        for (int c = 0; c < 128; c++) {
            float f = wf[o * 256 + c];
            #pragma unroll
            for (int i = 0; i < 8; i++) w1f[i] += f * w1s[c * 8 + i];
            cb += f * c1b[c];
        }
        float bs = bfv[o] + cb;
        #pragma unroll
        for (int i = 0; i < 8; i++) bs += w1f[i] * be1[i];

        for (int c = 0; c < 128; c++) Wc[o * 160 + c] = f2bf(wf[o * 256 + 128 + c]);
        #pragma unroll
        for (int i = 0; i < 8; i++) Wc[o * 160 + 128 + i] = f2bf(w1f[i] * s1[i]);
        Wc[o * 160 + 136] = f2bf(bs);
        for (int k = 137; k < 160; k++) Wc[o * 160 + k] = 0;
    }
    // wB cast: 256 threads x 64 elems, packed u32 stores
    {
        u32* wbo = (u32*)wBh;
        int base = t * 64;
        #pragma unroll
        for (int j = 0; j < 32; j++)
            wbo[(base >> 1) + j] = pack_rne(wB[base + 2 * j], wB[base + 2 * j + 1]);
    }
}

// ---------------- q = A3 @ x (bf16) --------------------
__global__ __launch_bounds__(256) void q_kernel(const float* __restrict__ x,
                                                const float* __restrict__ ws,
                                                u16* __restrict__ q)
{
    int t = blockIdx.x * 256 + threadIdx.x;
    int pt = t >> 6;
    int o = (t & 63) * 2;
    int b = pt >> 16, n = pt & 65535;
    const float* A3 = ws;
    float xv[8];
    #pragma unroll
    for (int i = 0; i < 8; i++) xv[i] = x[(((b << 3) + i) << 16) | n];
    float q0 = 0.f, q1 = 0.f;
    #pragma unroll
    for (int i = 0; i < 8; i++) {
        q0 += A3[o * 8 + i] * xv[i];
        q1 += A3[(o + 1) * 8 + i] * xv[i];
    }
    ((u32*)q)[t] = pack_rne(q0, q1);
}

// ---------------- heavy: barrier-free, LDS-free edge-conv + max-pool --------------
// 1 wave = 1 point at a time; A-frag (m=slot, k=channel) built in registers from
// gathered q rows; wB^T fragments persistent in VGPRs; 32 MFMA/point; max over
// slots = rows via 2 shfl_xor; NE written bf16 to global.
__global__ __launch_bounds__(256, 2) void heavy_kernel(
    const u16* __restrict__ q, const int* __restrict__ nbr,
    const u16* __restrict__ wBh, const u16* __restrict__ c3bf,
    u16* __restrict__ NEg)
{
    const uint4* qv = (const uint4*)q;
    int tid = threadIdx.x;
    int w = tid >> 6, l = tid & 63;
    int quad = l >> 4, l15 = l & 15;

    // persistent wB^T B-fragments: B[n=o=nt*16+l15][k=kt*32+quad*8+j]
    bf16x8 wBf[8][4];
    #pragma unroll
    for (int nt = 0; nt < 8; nt++)
        #pragma unroll
        for (int kt = 0; kt < 4; kt++) {
            U4 u; u.q = *(const uint4*)(wBh + (nt * 16 + l15) * 128 + kt * 32 + quad * 8);
            wBf[nt][kt] = u.v;
        }
    // persistent packed c3 at this lane's channels (kt*32+quad*8 ..+7)
    uint4 c3pk[4];
    #pragma unroll
    for (int kt = 0; kt < 4; kt++)
        c3pk[kt] = *(const uint4*)(c3bf + kt * 32 + quad * 8);

    int pbase = blockIdx.x * 64 + w * 16;      // 16 points per wave, batch-aligned
    int b = pbase >> 16;
    int n0 = pbase & 65535;
    int srow = (l15 < 15) ? l15 + 1 : 1;       // slot 15 duplicates neighbor row 1
    const int* nrow = nbr + ((((b << 4) + srow) << 16) + n0);

    // software pipeline: idx two ahead, qn/dd one ahead
    int idx1 = nrow[0];
    uint4 qnA[4], ddA[4];
    {
        const uint4* qrow = qv + (((size_t)((b << 16) | idx1)) << 4);
        qnA[0] = qrow[quad]; qnA[1] = qrow[4 + quad];
        qnA[2] = qrow[8 + quad]; qnA[3] = qrow[12 + quad];
        const uint4* crow = qv + (((size_t)pbase) << 4);
        #pragma unroll
        for (int kt = 0; kt < 4; kt++) {
            uint4 qc = crow[kt * 4 + quad];
            ddA[kt].x = dpair(c3pk[kt].x, qc.x);
            ddA[kt].y = dpair(c3pk[kt].y, qc.y);
            ddA[kt].z = dpair(c3pk[kt].z, qc.z);
            ddA[kt].w = dpair(c3pk[kt].w, qc.w);
        }
    }
    idx1 = nrow[1];

    #pragma unroll 2
    for (int i = 0; i < 16; ++i) {
        // prefetch next point's gathers (wrap on tail: harmless reload)
        uint4 qnB[4], qcB[4];
        {
            const uint4* qrow = qv + (((size_t)((b << 16) | idx1)) << 4);
            qnB[0] = qrow[quad]; qnB[1] = qrow[4 + quad];
            qnB[2] = qrow[8 + quad]; qnB[3] = qrow[12 + quad];
            const uint4* crow = qv + (((size_t)(pbase + ((i + 1) & 15))) << 4);
            qcB[0] = crow[quad]; qcB[1] = crow[4 + quad];
            qcB[2] = crow[8 + quad]; qcB[3] = crow[12 + quad];
        }
        idx1 = nrow[(i + 2) & 15];

        f32x4 acc[8];
        #pragma unroll
        for (int nt = 0; nt < 8; nt++) acc[nt] = (f32x4){0.f, 0.f, 0.f, 0.f};
        #pragma unroll
        for (int kt = 0; kt < 4; ++kt) {
            U4 fr;
            fr.q.x = zpair(qnA[kt].x, ddA[kt].x);
            fr.q.y = zpair(qnA[kt].y, ddA[kt].y);
            fr.q.z = zpair(qnA[kt].z, ddA[kt].z);
            fr.q.w = zpair(qnA[kt].w, ddA[kt].w);
            #pragma unroll
            for (int nt = 0; nt < 8; ++nt)
                acc[nt] = __builtin_amdgcn_mfma_f32_16x16x32_bf16(fr.v, wBf[nt][kt], acc[nt], 0, 0, 0);
        }
        // max over 16 slots (rows = quad*4+r), then bf16 NE store
        size_t pout = ((size_t)(pbase + i)) << 7;
        #pragma unroll
        for (int nt = 0; nt < 8; ++nt) {
            float m = fmaxf(fmaxf(acc[nt][0], acc[nt][1]), fmaxf(acc[nt][2], acc[nt][3]));
            m = fmaxf(m, __shfl_xor(m, 16, 64));
            m = fmaxf(m, __shfl_xor(m, 32, 64));
            if (l < 16) NEg[pout + nt * 16 + l] = (u16)((__float_as_uint(m) + 0x8000u) >> 16);
        }
        #pragma unroll
        for (int kt = 0; kt < 4; kt++) {
            qnA[kt] = qnB[kt];
            ddA[kt].x = dpair(c3pk[kt].x, qcB[kt].x);
            ddA[kt].y = dpair(c3pk[kt].y, qcB[kt].y);
            ddA[kt].z = dpair(c3pk[kt].z, qcB[kt].z);
            ddA[kt].w = dpair(c3pk[kt].w, qcB[kt].w);
        }
    }
}

// ---------------- combine: out = Wcat . [NE; x_bf16; 1; 0] --------------------
__global__ __launch_bounds__(256) void combine_kernel(
    const u16* __restrict__ NEg, const float* __restrict__ x,
    const u16* __restrict__ Wcat, float* __restrict__ out)
{
    __shared__ uint4 NExq[16 * 21];   // per point: 160 bf16 (NE|x|1|0), stride 21 granules
    int tid = threadIdx.x;
    int w = tid >> 6, l = tid & 63;
    int quad = l >> 4, l15 = l & 15;

    // persistent Wcat A-fragments: A[m=o'=w*32+mt*16+l15][k=kt*32+quad*8+j]
    bf16x8 Wcf[2][5];
    #pragma unroll
    for (int mt = 0; mt < 2; mt++)
        #pragma unroll
        for (int kt = 0; kt < 5; kt++) {
            U4 u; u.q = *(const uint4*)(Wcat + (w * 32 + mt * 16 + l15) * 160 + kt * 32 + quad * 8);
            Wcf[mt][kt] = u.v;
        }

    const uint4* NEv = (const uint4*)NEg;
    for (int it = 0; it < 4; ++it) {
        int group = blockIdx.x * 4 + it;        // 8192 groups of 16 points
        int b = group >> 12;
        int n0 = (group & 4095) << 4;
        int p0 = group << 4;
        __syncthreads();   // protect NExq rewrite vs previous readers
        {
            // 256 threads = 16 pts x 16 granules (128 bf16 NE per point)
            int pt = tid >> 4, g = tid & 15;
            NExq[pt * 21 + g] = NEv[((size_t)(p0 + pt) << 4) + g];
        }
        if (tid < 16) {
            int pt = tid;
            float xv[8];
            #pragma unroll
            for (int i = 0; i < 8; i++) xv[i] = x[((b * 8 + i) << 16) + n0 + pt];
            uint4 wx;
            wx.x = pack_rne(xv[0], xv[1]); wx.y = pack_rne(xv[2], xv[3]);
            wx.z = pack_rne(xv[4], xv[5]); wx.w = pack_rne(xv[6], xv[7]);
            NExq[pt * 21 + 16] = wx;
            NExq[pt * 21 + 17] = make_uint4(0x3F80u, 0u, 0u, 0u);
            NExq[pt * 21 + 18] = make_uint4(0u, 0u, 0u, 0u);
            NExq[pt * 21 + 19] = make_uint4(0u, 0u, 0u, 0u);
        }
        __syncthreads();
        f32x4 oa[2];
        oa[0] = (f32x4){0.f, 0.f, 0.f, 0.f};
        oa[1] = (f32x4){0.f, 0.f, 0.f, 0.f};
        #pragma unroll
        for (int kt = 0; kt < 5; ++kt) {
            U4 u; u.q = NExq[l15 * 21 + kt * 4 + quad];
            oa[0] = __builtin_amdgcn_mfma_f32_16x16x32_bf16(Wcf[0][kt], u.v, oa[0], 0, 0, 0);
            oa[1] = __builtin_amdgcn_mfma_f32_16x16x32_bf16(Wcf[1][kt], u.v, oa[1], 0, 0, 0);
        }
        #pragma unroll
        for (int mt = 0; mt < 2; ++mt) {
            int ob = w * 32 + mt * 16 + quad * 4;
            #pragma unroll
            for (int r = 0; r < 4; ++r)
                out[(((b << 7) + ob + r) << 16) + n0 + l15] = oa[mt][r];
        }
    }
}

extern "C" void kernel_launch(void* const* d_in, const int* in_sizes, int n_in,
                              void* d_out, int out_size, void* d_ws, size_t ws_size,
                              hipStream_t stream) {
    const float* x   = (const float*)d_in[0];
    const int*   nbr = (const int*)d_in[1];
    const float* g1  = (const float*)d_in[2];
    const float* b1  = (const float*)d_in[3];
    const float* m1  = (const float*)d_in[4];
    const float* v1  = (const float*)d_in[5];
    const float* w1  = (const float*)d_in[6];
    const float* c1b = (const float*)d_in[7];
    const float* g2  = (const float*)d_in[8];
    const float* b2  = (const float*)d_in[9];
    const float* m2  = (const float*)d_in[10];
    const float* v2  = (const float*)d_in[11];
    const float* wA  = (const float*)d_in[12];
    const float* g3  = (const float*)d_in[13];
    const float* b3  = (const float*)d_in[14];
    const float* m3  = (const float*)d_in[15];
    const float* v3  = (const float*)d_in[16];
    const float* wB  = (const float*)d_in[17];
    const float* wf  = (const float*)d_in[18];
    const float* bfv = (const float*)d_in[19];

    float* wsF  = (float*)d_ws;
    u16*   c3bf = (u16*)((char*)d_ws + WS_C3BF);
    u16*   wBh  = (u16*)((char*)d_ws + WS_WB);
    u16*   Wcat = (u16*)((char*)d_ws + WS_WCAT);
    u16*   q    = (u16*)((char*)d_ws + WS_Q);
    u16*   NEg  = (u16*)((char*)d_ws + WS_NE);
    float* out  = (float*)d_out;

    prep_kernel<<<1, 256, 0, stream>>>(g1, b1, m1, v1, w1, c1b, g2, b2, m2, v2,
                                       wA, g3, b3, m3, v3, wB, wf, bfv, wsF, c3bf, wBh, Wcat);
    q_kernel<<<32768, 256, 0, stream>>>(x, wsF, q);
    heavy_kernel<<<2048, 256, 0, stream>>>(q, nbr, wBh, c3bf, NEg);
    combine_kernel<<<2048, 256, 0, stream>>>(NEg, x, Wcat, out);
}